// Round 1
// 892.723 us; speedup vs baseline: 1.1424x; 1.1424x over previous
//
#include <hip/hip_runtime.h>
#include <math.h>

// ---------------------------------------------------------------------------
// TTT block, first-order expansion in lambda = LR*2/(B*D) = 1.2207e-6,
// chunked linear-attention form (chunk = 64 timesteps = 1024 rows):
//   H  = tanh(alpha1*x)                  rows r = t*16+b
//   TV = H@Wsᵀ + noise ; P = H@Wpᵀ ; E0 = TV@W0ᵀ - (TV - noise)
//   Cᵀ_j = E0ᵀ_j TV_j ; S'_i = W0 - lam * Σ_{j<i} Cᵀ_j  (excl prefix, fused W0)
//   x1_i = x + P_i@S'_iᵀ-form + Kp_i@E0_i,
//     Kp_i = -lam * mask16∘(P_i TV_iᵀ)  (triangular within chunk)
//   H2 = tanh(alpha2*x1) (fused into OUT epilogue)
//   out = gelu(H2@Wp1ᵀ)*(H2@Wp2ᵀ) + x1
//
// R1: 2-phase double-buffered K-loop (T3 minimum recipe): issue next-tile
//     global_load_lds BEFORE computing current tile; ONE barrier per K-step
//     (was: barrier → stage → drain-barrier → MFMA = fully exposed latency,
//     MfmaUtil 8.5%). Distinct __shared__ objects per buffer so the compiler
//     can't add alias-driven vmcnt waits before ds_reads. M_OUT's two phases
//     are flattened into one pipelined step space (no inter-phase drain).
// ---------------------------------------------------------------------------

typedef __bf16 bf16;
typedef __attribute__((ext_vector_type(8))) __bf16 bf16x8;
typedef __attribute__((ext_vector_type(4))) __bf16 bf16x4;
typedef __attribute__((ext_vector_type(4))) float f32x4;

#define LAM 1.220703125e-6f  // LR * 2 / (B*D)

enum { M_TV = 0, M_P = 1, M_E0 = 2, M_CT = 3, M_KP = 4, M_OUT = 5, M_U = 6 };

struct GA {
  const bf16* A;  int lda;   // phase-1 operands
  const bf16* B;  int ldb;
  const bf16* A2; int lda2;  // phase-2 A (M_OUT: P)
  const bf16* B2; int ldb2;  // phase-2 B (M_OUT: S')
  int K;
  const float* noise;
  const float* xin;
  const float* alpha2;
  const bf16* TVb;
  const bf16* Vb;
  bf16* H2b;
  float* outf;
  bf16* Cb; int ldc;
};

// async 16B global->LDS (lds dest = wave-uniform base + lane*16)
#define GLOAD_LDS16(gp, lp)                                                   \
  __builtin_amdgcn_global_load_lds(                                           \
      (const __attribute__((address_space(1))) unsigned int*)(gp),            \
      (__attribute__((address_space(3))) unsigned int*)(lp), 16, 0, 0)

// Stage one 128x32 A-tile + B-tile into the given LDS buffers (async).
__device__ __forceinline__ void stage_tiles(const bf16* __restrict__ Ap, int lda,
                                            const bf16* __restrict__ Bp, int ldb,
                                            int k0, bf16* As, bf16* Bs, int tid) {
  const int wv = tid >> 6, lane = tid & 63;
#pragma unroll
  for (int i = 0; i < 2; ++i) {
    int idx = (wv << 6) + lane + (i << 8);
    int row = idx >> 2;
    int k8 = (idx & 3) << 3;
    int lbase = ((wv << 6) + (i << 8)) << 3;  // wave-uniform LDS element base
    GLOAD_LDS16(Ap + (size_t)row * lda + k0 + k8, As + lbase);
    GLOAD_LDS16(Bp + (size_t)row * ldb + k0 + k8, Bs + lbase);
  }
}

// 16 MFMAs on one staged 128x32 tile pair.
__device__ __forceinline__ void compute_step(const bf16* As, const bf16* Bs,
                                             int wr, int wc, int m, int ko,
                                             f32x4 acc[4][4]) {
  bf16x8 af[4], bfr[4];
#pragma unroll
  for (int i = 0; i < 4; ++i)
    af[i] = *(const bf16x8*)(As + (wr + i * 16 + m) * 32 + ko * 8);
#pragma unroll
  for (int j = 0; j < 4; ++j)
    bfr[j] = *(const bf16x8*)(Bs + (wc + j * 16 + m) * 32 + ko * 8);
#pragma unroll
  for (int i = 0; i < 4; ++i) {
#pragma unroll
    for (int j = 0; j < 4; ++j)
      acc[i][j] =
          __builtin_amdgcn_mfma_f32_16x16x32_bf16(af[i], bfr[j], acc[i][j], 0, 0, 0);
  }
}

// Map pipeline step index -> segment (phase-1 or, for M_OUT, phase-2) and stage.
template <int MODE>
__device__ __forceinline__ void stage_sel(const GA& g, int s, int steps1,
                                          const bf16* A1, const bf16* B1,
                                          const bf16* A2, const bf16* B2,
                                          bf16* Asb, bf16* Bsb, int tid) {
  if constexpr (MODE == M_OUT) {
    if (s >= steps1) {
      stage_tiles(A2, g.lda2, B2, g.ldb2, (s - steps1) << 5, Asb, Bsb, tid);
      return;
    }
  }
  stage_tiles(A1, g.lda, B1, g.ldb, s << 5, Asb, Bsb, tid);
}

// NT GEMM: C[r,c] = sum_k A[r,k]*B[c,k]; 128x128 tile, 256 threads (4 waves).
// blockIdx.z batches chunks for M_CT / M_KP / M_OUT.
template <int MODE>
__global__ __launch_bounds__(256) void gemm_nt(GA g) {
  __shared__ __attribute__((aligned(16))) bf16 As0[128 * 32];
  __shared__ __attribute__((aligned(16))) bf16 Bs0[128 * 32];
  __shared__ __attribute__((aligned(16))) bf16 As1[128 * 32];
  __shared__ __attribute__((aligned(16))) bf16 Bs1[128 * 32];

  const int bx = blockIdx.x, by = blockIdx.y, bz = blockIdx.z;
  const int c0 = bx << 7;
  const int r0 = by << 7;  // row-tile within chunk (or global when z==1)
  if constexpr (MODE == M_KP) {
    if (c0 > r0) return;  // strictly-above-diagonal tiles never read
  }

  size_t zA = 0, zB = 0, zC = 0;
  if constexpr (MODE == M_CT) { zA = (size_t)bz << 10; zB = zA; zC = (size_t)bz << 20; }
  if constexpr (MODE == M_KP) { zA = (size_t)bz << 20; zB = zA; zC = zA; }
  if constexpr (MODE == M_OUT) { zA = (size_t)bz << 20; zB = (size_t)bz << 10; }

  const int tid = threadIdx.x;
  const int lane = tid & 63, wv = tid >> 6;
  const int wr = (wv >> 1) << 6, wc = (wv & 1) << 6;
  const int m = lane & 15, ko = lane >> 4;

  f32x4 acc[4][4];
#pragma unroll
  for (int i = 0; i < 4; ++i) {
#pragma unroll
    for (int j = 0; j < 4; ++j) acc[i][j] = (f32x4){0.f, 0.f, 0.f, 0.f};
  }

  int K1 = g.K;
  if constexpr (MODE == M_OUT) K1 = r0 + 128;  // triangular (Kp cols > r0+127 are 0)
  const int steps1 = K1 >> 5;

  const bf16* A1 = g.A + zA + (size_t)r0 * g.lda;
  const bf16* B1 = g.B + zB + (size_t)c0 * g.ldb;
  const bf16* A2 = nullptr;
  const bf16* B2 = nullptr;
  int total = steps1;
  if constexpr (MODE == M_OUT) {
    A2 = g.A2 + zA + (size_t)r0 * g.lda2;
    B2 = g.B2 + zA + (size_t)c0 * g.ldb2;  // S' chunk bz
    total += 32;                            // phase-2: K=1024, BK=32
  }

  // -------- 2-phase double-buffered pipeline (1 barrier / K-step) --------
  // total is even for every launch config (steps1 ∈ {4,8,..,32}; +32 for OUT),
  // but the tail below also handles odd counts defensively.
  stage_sel<MODE>(g, 0, steps1, A1, B1, A2, B2, As0, Bs0, tid);
  __syncthreads();  // compiler emits vmcnt(0) drain before s_barrier

  int s = 0;
  for (; s + 2 < total; s += 2) {
    stage_sel<MODE>(g, s + 1, steps1, A1, B1, A2, B2, As1, Bs1, tid);
    compute_step(As0, Bs0, wr, wc, m, ko, acc);
    __syncthreads();
    stage_sel<MODE>(g, s + 2, steps1, A1, B1, A2, B2, As0, Bs0, tid);
    compute_step(As1, Bs1, wr, wc, m, ko, acc);
    __syncthreads();
  }
  if (s + 1 < total) {  // two steps left
    stage_sel<MODE>(g, s + 1, steps1, A1, B1, A2, B2, As1, Bs1, tid);
    compute_step(As0, Bs0, wr, wc, m, ko, acc);
    __syncthreads();
    compute_step(As1, Bs1, wr, wc, m, ko, acc);
  } else {              // one step left
    compute_step(As0, Bs0, wr, wc, m, ko, acc);
  }

  // C/D layout (m89/m91-verified): col = lane&15, row = (lane>>4)*4 + reg
#pragma unroll
  for (int i = 0; i < 4; ++i) {
#pragma unroll
    for (int j = 0; j < 4; ++j) {
      const int gc = c0 + wc + j * 16 + m;
#pragma unroll
      for (int rg = 0; rg < 4; ++rg) {
        const int grl = r0 + wr + i * 16 + ko * 4 + rg;
        float v = acc[i][j][rg];
        if constexpr (MODE == M_TV) {
          int t = grl >> 4, b = grl & 15;
          float tv = v + g.noise[((size_t)b << 20) + ((size_t)t << 10) + gc];
          g.Cb[(size_t)grl * g.ldc + gc] = (bf16)tv;
        } else if constexpr (MODE == M_P) {
          g.Cb[(size_t)grl * g.ldc + gc] = (bf16)v;
        } else if constexpr (MODE == M_CT) {
          g.Cb[zC + (size_t)grl * g.ldc + gc] = (bf16)v;
        } else if constexpr (MODE == M_E0) {
          int t = grl >> 4, b = grl & 15;
          size_t ni = ((size_t)b << 20) + ((size_t)t << 10) + gc;
          float tvv = (float)g.TVb[(size_t)grl * 1024 + gc];
          float e0 = v - (tvv - g.noise[ni]);  // state = tv - noise
          g.Cb[(size_t)grl * g.ldc + gc] = (bf16)e0;
        } else if constexpr (MODE == M_KP) {
          float sv = ((gc >> 4) <= (grl >> 4)) ? (-LAM * v) : 0.0f;
          g.Cb[zC + (size_t)grl * g.ldc + gc] = (bf16)sv;
        } else if constexpr (MODE == M_OUT) {
          int rgl = (bz << 10) + grl;
          int t = rgl >> 4, b = rgl & 15;
          size_t oi = ((size_t)b << 20) + ((size_t)t << 10) + gc;
          float x1 = v + g.xin[oi];
          g.outf[oi] = x1;
          g.H2b[oi] = (bf16)tanhf(g.alpha2[gc] * x1);  // fused norm_2
        } else if constexpr (MODE == M_U) {
          size_t oi = (size_t)grl * 1024 + gc;
          float u = v;
          float gl = 0.5f * u * (1.0f + erff(u * 0.70710678118654752f));
          g.outf[oi] = gl * (float)g.Vb[oi] + g.outf[oi];
        }
      }
    }
  }
}

// fp32 -> bf16 of the 5 weight matrices (concatenated dst)
__global__ void ew_convert(const float* w0, const float* w1, const float* w2,
                           const float* w3, const float* w4, bf16* dst) {
  int gid = blockIdx.x * 256 + threadIdx.x;
  int i4 = gid << 2;
  int mm = i4 >> 20;
  const float* src = (mm == 0) ? w0 : (mm == 1) ? w1 : (mm == 2) ? w2
                     : (mm == 3) ? w3 : w4;
  int off = i4 & 1048575;
  float4 v = *(const float4*)(src + off);
  bf16x4 o;
  o[0] = (bf16)v.x; o[1] = (bf16)v.y; o[2] = (bf16)v.z; o[3] = (bf16)v.w;
  *(bf16x4*)(dst + i4) = o;
}

// H[(t*16+b), d] = bf16(tanh(alpha1[d] * x[b,t,d]))
__global__ void ew_h1(const float* __restrict__ x, const float* __restrict__ a1,
                      bf16* __restrict__ H) {
  int gid = blockIdx.x * 256 + threadIdx.x;
  int i4 = gid << 2;
  int d = i4 & 1023;
  int t = (i4 >> 10) & 1023;
  int b = i4 >> 20;
  float4 xv = *(const float4*)(x + i4);
  float4 av = *(const float4*)(a1 + d);
  bf16x4 o;
  o[0] = (bf16)tanhf(av.x * xv.x);
  o[1] = (bf16)tanhf(av.y * xv.y);
  o[2] = (bf16)tanhf(av.z * xv.z);
  o[3] = (bf16)tanhf(av.w * xv.w);
  *(bf16x4*)(H + (((size_t)((t << 4) + b)) << 10) + d) = o;
}

// S'[j] = W0 - lam * (exclusive prefix of C over chunks); in-place safe
__global__ void prefix_s(const bf16* __restrict__ C, bf16* __restrict__ S,
                         const bf16* __restrict__ W0) {
  int gid = blockIdx.x * 256 + threadIdx.x;  // 262144 threads
  size_t base = (size_t)gid << 2;
  bf16x4 wv = *(const bf16x4*)(W0 + base);
  float w0 = (float)wv[0], w1 = (float)wv[1], w2 = (float)wv[2],
        w3 = (float)wv[3];
  float ac0 = 0.f, ac1 = 0.f, ac2 = 0.f, ac3 = 0.f;
#pragma unroll
  for (int j = 0; j < 16; ++j) {
    size_t off = ((size_t)j << 20) + base;
    bf16x4 c = *(const bf16x4*)(C + off);
    bf16x4 o;
    o[0] = (bf16)(w0 - LAM * ac0);
    o[1] = (bf16)(w1 - LAM * ac1);
    o[2] = (bf16)(w2 - LAM * ac2);
    o[3] = (bf16)(w3 - LAM * ac3);
    *(bf16x4*)(S + off) = o;
    ac0 += (float)c[0]; ac1 += (float)c[1];
    ac2 += (float)c[2]; ac3 += (float)c[3];
  }
}

// [16384 x 1024] -> [1024 x 16384] bf16 transpose, 64x64 LDS tiles
__global__ __launch_bounds__(256) void tr_e0(const bf16* __restrict__ in,
                                             bf16* __restrict__ out) {
  __shared__ bf16 tile[64][72];
  int c0 = blockIdx.x << 6;
  int r0 = blockIdx.y << 6;
  int tid = threadIdx.x;
  int lr = tid >> 4;
  int lc = (tid & 15) << 2;
#pragma unroll
  for (int ph = 0; ph < 4; ++ph) {
    int row = lr + (ph << 4);
    bf16x4 v = *(const bf16x4*)(in + (size_t)(r0 + row) * 1024 + c0 + lc);
    *(bf16x4*)(&tile[row][lc]) = v;
  }
  __syncthreads();
#pragma unroll
  for (int ph = 0; ph < 4; ++ph) {
    int oc = lr + (ph << 4);
    bf16x4 v;
    v[0] = tile[lc + 0][oc];
    v[1] = tile[lc + 1][oc];
    v[2] = tile[lc + 2][oc];
    v[3] = tile[lc + 3][oc];
    *(bf16x4*)(out + (size_t)(c0 + oc) * 16384 + r0 + lc) = v;
  }
}

extern "C" void kernel_launch(void* const* d_in, const int* in_sizes, int n_in,
                              void* d_out, int out_size, void* d_ws,
                              size_t ws_size, hipStream_t stream) {
  (void)in_sizes; (void)n_in; (void)out_size;
  const float* x = (const float*)d_in[0];
  const float* noise = (const float*)d_in[1];
  const float* a1 = (const float*)d_in[2];
  const float* a2 = (const float*)d_in[3];
  const float* Wmap = (const float*)d_in[4];
  const float* Wst = (const float*)d_in[5];
  const float* Wpr = (const float*)d_in[6];
  const float* Wp1 = (const float*)d_in[7];
  const float* Wp2 = (const float*)d_in[8];
  float* out = (float*)d_out;

  const size_t MB32 = (size_t)16384 * 1024 * 2;  // 32 MiB
  const size_t NEED = 5 * MB32 + 5 * (size_t)1048576 * 2;  // 170 MiB
  if (ws_size < NEED) return;  // insufficient scratch; fail loudly

  char* ws = (char*)d_ws;
  bf16* s0 = (bf16*)(ws);              // H -> E0 -> C^T -> S' -> V
  bf16* s1 = (bf16*)(ws + MB32);       // TV -> H2
  bf16* s2 = (bf16*)(ws + 2 * MB32);   // P
  bf16* s3 = (bf16*)(ws + 3 * MB32);   // E0^T [1024 x 16384]
  bf16* s4 = (bf16*)(ws + 4 * MB32);   // TV^T -> Kp[16][1024][1024]
  bf16* Wcat = (bf16*)(ws + 5 * MB32);
  bf16* Wb0 = Wcat;
  bf16* Wsb = Wcat + (1 << 20);
  bf16* Wpb = Wcat + 2 * (1 << 20);
  bf16* W1b = Wcat + 3 * (1 << 20);
  bf16* W2b = Wcat + 4 * (1 << 20);

  ew_convert<<<5120, 256, 0, stream>>>(Wmap, Wst, Wpr, Wp1, Wp2, Wcat);
  ew_h1<<<16384, 256, 0, stream>>>(x, a1, s0);

  {  // TV = H@Wsᵀ + noise -> s1
    GA g{};
    g.A = s0; g.lda = 1024; g.B = Wsb; g.ldb = 1024; g.K = 1024;
    g.noise = noise; g.Cb = s1; g.ldc = 1024;
    gemm_nt<M_TV><<<dim3(8, 128), 256, 0, stream>>>(g);
  }
  {  // P = H@Wpᵀ -> s2
    GA g{};
    g.A = s0; g.lda = 1024; g.B = Wpb; g.ldb = 1024; g.K = 1024;
    g.Cb = s2; g.ldc = 1024;
    gemm_nt<M_P><<<dim3(8, 128), 256, 0, stream>>>(g);
  }
  {  // E0 = TV@W0ᵀ - (TV - noise) -> s0 (H dead)
    GA g{};
    g.A = s1; g.lda = 1024; g.B = Wb0; g.ldb = 1024; g.K = 1024;
    g.noise = noise; g.TVb = s1; g.Cb = s0; g.ldc = 1024;
    gemm_nt<M_E0><<<dim3(8, 128), 256, 0, stream>>>(g);
  }
  tr_e0<<<dim3(16, 256), 256, 0, stream>>>(s0, s3);  // E0^T  (s0 free)
  tr_e0<<<dim3(16, 256), 256, 0, stream>>>(s1, s4);  // TV^T

  {  // C^T_j[r,c] = sum_n E0[n,r]*TV[n,c] -> s0[j]
    GA g{};
    g.A = s3; g.lda = 16384; g.B = s4; g.ldb = 16384; g.K = 1024;
    g.Cb = s0; g.ldc = 1024;
    gemm_nt<M_CT><<<dim3(8, 8, 16), 256, 0, stream>>>(g);
  }
  prefix_s<<<1024, 256, 0, stream>>>(s0, s0, Wb0);  // S' = W0 - lam*prefix

  {  // Kp_i = -lam * mask16 ∘ (P_i @ TV_iᵀ) -> s4 (TV^T dead)
    GA g{};
    g.A = s2; g.lda = 1024; g.B = s1; g.ldb = 1024; g.K = 1024;
    g.Cb = s4; g.ldc = 1024;
    gemm_nt<M_KP><<<dim3(8, 8, 16), 256, 0, stream>>>(g);
  }
  {  // x1_i = Kp_i@E0_i (tri-K) + P_i@S'_i + x -> d_out ; H2 -> s1
    GA g{};
    g.A = s4; g.lda = 1024;        // Kp chunk
    g.B = s3; g.ldb = 16384;       // E0^T (chunk col offset via z)
    g.A2 = s2; g.lda2 = 1024;      // P chunk
    g.B2 = s0; g.ldb2 = 1024;      // S' chunk
    g.xin = x; g.outf = out;
    g.alpha2 = a2; g.H2b = s1;     // fused tanh(alpha2*x1) (TV dead)
    gemm_nt<M_OUT><<<dim3(8, 8, 16), 256, 0, stream>>>(g);
  }

  {  // V = H2@Wp2ᵀ -> s0 (S' dead)
    GA g{};
    g.A = s1; g.lda = 1024; g.B = W2b; g.ldb = 1024; g.K = 1024;
    g.Cb = s0; g.ldc = 1024;
    gemm_nt<M_P><<<dim3(8, 128), 256, 0, stream>>>(g);
  }
  {  // out = gelu(H2@Wp1ᵀ)*V + x1
    GA g{};
    g.A = s1; g.lda = 1024; g.B = W1b; g.ldb = 1024; g.K = 1024;
    g.Vb = s0; g.outf = out;
    gemm_nt<M_U><<<dim3(8, 128), 256, 0, stream>>>(g);
  }
}

// Round 3
// 852.954 us; speedup vs baseline: 1.1956x; 1.0466x over previous
//
#include <hip/hip_runtime.h>
#include <math.h>

// ---------------------------------------------------------------------------
// TTT block, first-order expansion in lambda = LR*2/(B*D) = 1.2207e-6,
// chunked linear-attention form (chunk = 64 timesteps = 1024 rows):
//   H  = tanh(alpha1*x)                  rows r = t*16+b
//   TV = H@Wsᵀ + noise ; P = H@Wpᵀ ; E0 = TV@W0ᵀ - (TV - noise)
//   Cᵀ_j = E0ᵀ_j TV_j ; S'_i = W0 - lam * Σ_{j<i} Cᵀ_j  (excl prefix, fused W0)
//   x1_i = x + P_i@S'_iᵀ-form + Kp_i@E0_i,
//     Kp_i = -lam * mask16∘(P_i TV_iᵀ)  (triangular within chunk)
//   H2 = tanh(alpha2*x1) (fused into OUT epilogue)
//   out = gelu(H2@Wp1ᵀ)*(H2@Wp2ᵀ) + x1
//
// R3 (= R2 hardened; R2 bench died to container failure, no kernel signal):
//   ring-4 LDS buffers, prefetch distance 2, counted s_waitcnt vmcnt(8)
//   (never 0 in-loop) so 2 K-steps of global_load_lds stay in flight across
//   barriers (T4). FIX vs R2: waitcnt+s_barrier fused into ONE asm volatile
//   with "memory" clobber + sched_barrier(0) after — rule #18-class hazard:
//   a ds_read could otherwise be scheduled between waitcnt and barrier and
//   read rows staged by OTHER waves before their loads landed.
//   T2 swizzle via pre-swizzled GLOBAL source (LDS dest stays linear, rule
//   #21): granule g of row r holds k-block g ^ ((r>>1)&3); read applies the
//   same XOR. T5 setprio around MFMA cluster. T1 bijective XCD block swizzle.
//   Ring-4/D=2 race proof: stage(s+2) overwrites buf[(s-2)&3], last read by
//   compute(s-2); every wave passed barrier(s-1) only after compute(s-2)'s
//   ds_reads completed everywhere, and stage(s+2) issues after barrier(s-1).
// ---------------------------------------------------------------------------

typedef __bf16 bf16;
typedef __attribute__((ext_vector_type(8))) __bf16 bf16x8;
typedef __attribute__((ext_vector_type(4))) __bf16 bf16x4;
typedef __attribute__((ext_vector_type(4))) float f32x4;

#define LAM 1.220703125e-6f  // LR * 2 / (B*D)

enum { M_TV = 0, M_P = 1, M_E0 = 2, M_CT = 3, M_KP = 4, M_OUT = 5, M_U = 6 };

struct GA {
  const bf16* A;  int lda;   // phase-1 operands
  const bf16* B;  int ldb;
  const bf16* A2; int lda2;  // phase-2 A (M_OUT: P)
  const bf16* B2; int ldb2;  // phase-2 B (M_OUT: S')
  int K;
  const float* noise;
  const float* xin;
  const float* alpha2;
  const bf16* TVb;
  const bf16* Vb;
  bf16* H2b;
  float* outf;
  bf16* Cb; int ldc;
};

// async 16B global->LDS (lds dest = wave-uniform base + lane*16)
#define GLOAD_LDS16(gp, lp)                                                   \
  __builtin_amdgcn_global_load_lds(                                           \
      (const __attribute__((address_space(1))) unsigned int*)(gp),            \
      (__attribute__((address_space(3))) unsigned int*)(lp), 16, 0, 0)

// Fused counted-wait + workgroup barrier. Single asm block so NOTHING can be
// scheduled between the waitcnt and the s_barrier, and the "memory" clobber
// keeps every LDS/global access on its own side. sched_barrier(0) pins the
// machine scheduler too (rule #18).
#define WAIT_BARRIER(N)                                                       \
  do {                                                                        \
    asm volatile("s_waitcnt vmcnt(" #N ")\n\ts_barrier" ::: "memory");        \
    __builtin_amdgcn_sched_barrier(0);                                        \
  } while (0)

// Stage one 128x32 A-tile + B-tile into LDS ring slot (async, 4 vmem/lane).
// LDS layout stays linear (chunk c -> row=c>>2, granule=c&3); the SOURCE
// k-block is swizzled: granule g of row r holds k-block g ^ ((r>>1)&3).
__device__ __forceinline__ void stage_tiles(const bf16* __restrict__ Ap, int lda,
                                            const bf16* __restrict__ Bp, int ldb,
                                            int k0, bf16* As, bf16* Bs, int tid) {
#pragma unroll
  for (int rr = 0; rr < 2; ++rr) {
    int c = tid + (rr << 8);                    // chunk 0..511 (16B each)
    int row = c >> 2;
    int kb = (c & 3) ^ ((c >> 3) & 3);          // (c>>3)&3 == (row>>1)&3
    int lbase = ((tid & 192) + (rr << 8)) << 3; // wave-uniform LDS elem base
    GLOAD_LDS16(Ap + (size_t)row * lda + k0 + (kb << 3), As + lbase);
    GLOAD_LDS16(Bp + (size_t)row * ldb + k0 + (kb << 3), Bs + lbase);
  }
}

// 16 MFMAs on one staged 128x32 tile pair. gsw = ko ^ ((m>>1)&3) (swizzle).
__device__ __forceinline__ void compute_step(const bf16* As, const bf16* Bs,
                                             int wr, int wc, int m, int gsw,
                                             f32x4 acc[4][4]) {
  bf16x8 af[4], bfr[4];
#pragma unroll
  for (int i = 0; i < 4; ++i)
    af[i] = *(const bf16x8*)(As + (wr + i * 16 + m) * 32 + (gsw << 3));
#pragma unroll
  for (int j = 0; j < 4; ++j)
    bfr[j] = *(const bf16x8*)(Bs + (wc + j * 16 + m) * 32 + (gsw << 3));
  __builtin_amdgcn_s_setprio(1);
#pragma unroll
  for (int i = 0; i < 4; ++i) {
#pragma unroll
    for (int j = 0; j < 4; ++j)
      acc[i][j] =
          __builtin_amdgcn_mfma_f32_16x16x32_bf16(af[i], bfr[j], acc[i][j], 0, 0, 0);
  }
  __builtin_amdgcn_s_setprio(0);
}

// Map pipeline step index -> segment (phase-1 or, for M_OUT, phase-2) and stage.
template <int MODE>
__device__ __forceinline__ void stage_sel(const GA& g, int s, int steps1,
                                          const bf16* A1, const bf16* B1,
                                          const bf16* A2, const bf16* B2,
                                          bf16* Asb, bf16* Bsb, int tid) {
  if constexpr (MODE == M_OUT) {
    if (s >= steps1) {
      stage_tiles(A2, g.lda2, B2, g.ldb2, (s - steps1) << 5, Asb, Bsb, tid);
      return;
    }
  }
  stage_tiles(A1, g.lda, B1, g.ldb, s << 5, Asb, Bsb, tid);
}

// NT GEMM: C[r,c] = sum_k A[r,k]*B[c,k]; 128x128 tile, 256 threads (4 waves).
// blockIdx.z batches chunks for M_CT / M_KP / M_OUT.
template <int MODE>
__global__ __launch_bounds__(256) void gemm_nt(GA g) {
  __shared__ __attribute__((aligned(16))) bf16 As[4][128 * 32];
  __shared__ __attribute__((aligned(16))) bf16 Bs[4][128 * 32];

  // T1: bijective XCD-chunk swizzle of the flat block id (all grids %8 == 0).
  const int gx = gridDim.x, gy = gridDim.y;
  const int nwg = gx * gy * (int)gridDim.z;
  int flat = blockIdx.x + gx * (blockIdx.y + gy * blockIdx.z);
  int swz = (flat & 7) * (nwg >> 3) + (flat >> 3);
  const int bx = swz % gx;
  int t1v = swz / gx;
  const int by = t1v % gy;
  const int bz = t1v / gy;

  const int c0 = bx << 7;
  const int r0 = by << 7;  // row-tile within chunk (or global when z==1)
  if constexpr (MODE == M_KP) {
    if (c0 > r0) return;  // strictly-above-diagonal tiles never read
  }

  size_t zA = 0, zB = 0, zC = 0;
  if constexpr (MODE == M_CT) { zA = (size_t)bz << 10; zB = zA; zC = (size_t)bz << 20; }
  if constexpr (MODE == M_KP) { zA = (size_t)bz << 20; zB = zA; zC = zA; }
  if constexpr (MODE == M_OUT) { zA = (size_t)bz << 20; zB = (size_t)bz << 10; }

  const int tid = threadIdx.x;
  const int lane = tid & 63, wv = tid >> 6;
  const int wr = (wv >> 1) << 6, wc = (wv & 1) << 6;
  const int m = lane & 15, ko = lane >> 4;
  const int gsw = ko ^ ((m >> 1) & 3);  // swizzled read granule

  f32x4 acc[4][4];
#pragma unroll
  for (int i = 0; i < 4; ++i) {
#pragma unroll
    for (int j = 0; j < 4; ++j) acc[i][j] = (f32x4){0.f, 0.f, 0.f, 0.f};
  }

  int K1 = g.K;
  if constexpr (MODE == M_OUT) K1 = r0 + 128;  // triangular (Kp cols > r0+127 are 0)
  const int steps1 = K1 >> 5;

  const bf16* A1 = g.A + zA + (size_t)r0 * g.lda;
  const bf16* B1 = g.B + zB + (size_t)c0 * g.ldb;
  const bf16* A2 = nullptr;
  const bf16* B2 = nullptr;
  int total = steps1;
  if constexpr (MODE == M_OUT) {
    A2 = g.A2 + zA + (size_t)r0 * g.lda2;
    B2 = g.B2 + zA + (size_t)c0 * g.ldb2;  // S' chunk bz
    total += 32;                            // phase-2: K=1024, BK=32
  }
  // total >= 32 for every launch config.

  // -------- ring-4 pipeline, prefetch distance 2, counted vmcnt --------
  stage_sel<MODE>(g, 0, steps1, A1, B1, A2, B2, As[0], Bs[0], tid);
  stage_sel<MODE>(g, 1, steps1, A1, B1, A2, B2, As[1], Bs[1], tid);

  int s = 0;
  for (; s < total - 2; ++s) {
    const int rn = (s + 2) & 3;
    stage_sel<MODE>(g, s + 2, steps1, A1, B1, A2, B2, As[rn], Bs[rn], tid);
    // wait: stage(s) landed (stages s+1,s+2 = 8 vmem/lane may stay in flight)
    WAIT_BARRIER(8);
    compute_step(As[s & 3], Bs[s & 3], wr, wc, m, gsw, acc);
  }
  // s == total-2: only stage(total-1) still in flight after this wait
  WAIT_BARRIER(4);
  compute_step(As[s & 3], Bs[s & 3], wr, wc, m, gsw, acc);
  ++s;
  WAIT_BARRIER(0);
  compute_step(As[s & 3], Bs[s & 3], wr, wc, m, gsw, acc);

  // C/D layout (m89/m91-verified): col = lane&15, row = (lane>>4)*4 + reg
#pragma unroll
  for (int i = 0; i < 4; ++i) {
#pragma unroll
    for (int j = 0; j < 4; ++j) {
      const int gc = c0 + wc + j * 16 + m;
#pragma unroll
      for (int rg = 0; rg < 4; ++rg) {
        const int grl = r0 + wr + i * 16 + ko * 4 + rg;
        float v = acc[i][j][rg];
        if constexpr (MODE == M_TV) {
          int t = grl >> 4, b = grl & 15;
          float tv = v + g.noise[((size_t)b << 20) + ((size_t)t << 10) + gc];
          g.Cb[(size_t)grl * g.ldc + gc] = (bf16)tv;
        } else if constexpr (MODE == M_P) {
          g.Cb[(size_t)grl * g.ldc + gc] = (bf16)v;
        } else if constexpr (MODE == M_CT) {
          g.Cb[zC + (size_t)grl * g.ldc + gc] = (bf16)v;
        } else if constexpr (MODE == M_E0) {
          int t = grl >> 4, b = grl & 15;
          size_t ni = ((size_t)b << 20) + ((size_t)t << 10) + gc;
          float tvv = (float)g.TVb[(size_t)grl * 1024 + gc];
          float e0 = v - (tvv - g.noise[ni]);  // state = tv - noise
          g.Cb[(size_t)grl * g.ldc + gc] = (bf16)e0;
        } else if constexpr (MODE == M_KP) {
          float sv = ((gc >> 4) <= (grl >> 4)) ? (-LAM * v) : 0.0f;
          g.Cb[zC + (size_t)grl * g.ldc + gc] = (bf16)sv;
        } else if constexpr (MODE == M_OUT) {
          int rgl = (bz << 10) + grl;
          int t = rgl >> 4, b = rgl & 15;
          size_t oi = ((size_t)b << 20) + ((size_t)t << 10) + gc;
          float x1 = v + g.xin[oi];
          g.outf[oi] = x1;
          g.H2b[oi] = (bf16)tanhf(g.alpha2[gc] * x1);  // fused norm_2
        } else if constexpr (MODE == M_U) {
          size_t oi = (size_t)grl * 1024 + gc;
          float u = v;
          float gl = 0.5f * u * (1.0f + erff(u * 0.70710678118654752f));
          g.outf[oi] = gl * (float)g.Vb[oi] + g.outf[oi];
        }
      }
    }
  }
}

// fp32 -> bf16 of the 5 weight matrices (concatenated dst)
__global__ void ew_convert(const float* w0, const float* w1, const float* w2,
                           const float* w3, const float* w4, bf16* dst) {
  int gid = blockIdx.x * 256 + threadIdx.x;
  int i4 = gid << 2;
  int mm = i4 >> 20;
  const float* src = (mm == 0) ? w0 : (mm == 1) ? w1 : (mm == 2) ? w2
                     : (mm == 3) ? w3 : w4;
  int off = i4 & 1048575;
  float4 v = *(const float4*)(src + off);
  bf16x4 o;
  o[0] = (bf16)v.x; o[1] = (bf16)v.y; o[2] = (bf16)v.z; o[3] = (bf16)v.w;
  *(bf16x4*)(dst + i4) = o;
}

// H[(t*16+b), d] = bf16(tanh(alpha1[d] * x[b,t,d]))
__global__ void ew_h1(const float* __restrict__ x, const float* __restrict__ a1,
                      bf16* __restrict__ H) {
  int gid = blockIdx.x * 256 + threadIdx.x;
  int i4 = gid << 2;
  int d = i4 & 1023;
  int t = (i4 >> 10) & 1023;
  int b = i4 >> 20;
  float4 xv = *(const float4*)(x + i4);
  float4 av = *(const float4*)(a1 + d);
  bf16x4 o;
  o[0] = (bf16)tanhf(av.x * xv.x);
  o[1] = (bf16)tanhf(av.y * xv.y);
  o[2] = (bf16)tanhf(av.z * xv.z);
  o[3] = (bf16)tanhf(av.w * xv.w);
  *(bf16x4*)(H + (((size_t)((t << 4) + b)) << 10) + d) = o;
}

// S'[j] = W0 - lam * (exclusive prefix of C over chunks); in-place safe
__global__ void prefix_s(const bf16* __restrict__ C, bf16* __restrict__ S,
                         const bf16* __restrict__ W0) {
  int gid = blockIdx.x * 256 + threadIdx.x;  // 262144 threads
  size_t base = (size_t)gid << 2;
  bf16x4 wv = *(const bf16x4*)(W0 + base);
  float w0 = (float)wv[0], w1 = (float)wv[1], w2 = (float)wv[2],
        w3 = (float)wv[3];
  float ac0 = 0.f, ac1 = 0.f, ac2 = 0.f, ac3 = 0.f;
#pragma unroll
  for (int j = 0; j < 16; ++j) {
    size_t off = ((size_t)j << 20) + base;
    bf16x4 c = *(const bf16x4*)(C + off);
    bf16x4 o;
    o[0] = (bf16)(w0 - LAM * ac0);
    o[1] = (bf16)(w1 - LAM * ac1);
    o[2] = (bf16)(w2 - LAM * ac2);
    o[3] = (bf16)(w3 - LAM * ac3);
    *(bf16x4*)(S + off) = o;
    ac0 += (float)c[0]; ac1 += (float)c[1];
    ac2 += (float)c[2]; ac3 += (float)c[3];
  }
}

// [16384 x 1024] -> [1024 x 16384] bf16 transpose, 64x64 LDS tiles
__global__ __launch_bounds__(256) void tr_e0(const bf16* __restrict__ in,
                                             bf16* __restrict__ out) {
  __shared__ bf16 tile[64][72];
  int c0 = blockIdx.x << 6;
  int r0 = blockIdx.y << 6;
  int tid = threadIdx.x;
  int lr = tid >> 4;
  int lc = (tid & 15) << 2;
#pragma unroll
  for (int ph = 0; ph < 4; ++ph) {
    int row = lr + (ph << 4);
    bf16x4 v = *(const bf16x4*)(in + (size_t)(r0 + row) * 1024 + c0 + lc);
    *(bf16x4*)(&tile[row][lc]) = v;
  }
  __syncthreads();
#pragma unroll
  for (int ph = 0; ph < 4; ++ph) {
    int oc = lr + (ph << 4);
    bf16x4 v;
    v[0] = tile[lc + 0][oc];
    v[1] = tile[lc + 1][oc];
    v[2] = tile[lc + 2][oc];
    v[3] = tile[lc + 3][oc];
    *(bf16x4*)(out + (size_t)(c0 + oc) * 16384 + r0 + lc) = v;
  }
}

extern "C" void kernel_launch(void* const* d_in, const int* in_sizes, int n_in,
                              void* d_out, int out_size, void* d_ws,
                              size_t ws_size, hipStream_t stream) {
  (void)in_sizes; (void)n_in; (void)out_size;
  const float* x = (const float*)d_in[0];
  const float* noise = (const float*)d_in[1];
  const float* a1 = (const float*)d_in[2];
  const float* a2 = (const float*)d_in[3];
  const float* Wmap = (const float*)d_in[4];
  const float* Wst = (const float*)d_in[5];
  const float* Wpr = (const float*)d_in[6];
  const float* Wp1 = (const float*)d_in[7];
  const float* Wp2 = (const float*)d_in[8];
  float* out = (float*)d_out;

  const size_t MB32 = (size_t)16384 * 1024 * 2;  // 32 MiB
  const size_t NEED = 5 * MB32 + 5 * (size_t)1048576 * 2;  // 170 MiB
  if (ws_size < NEED) return;  // insufficient scratch; fail loudly

  char* ws = (char*)d_ws;
  bf16* s0 = (bf16*)(ws);              // H -> E0 -> C^T -> S' -> V
  bf16* s1 = (bf16*)(ws + MB32);       // TV -> H2
  bf16* s2 = (bf16*)(ws + 2 * MB32);   // P
  bf16* s3 = (bf16*)(ws + 3 * MB32);   // E0^T [1024 x 16384]
  bf16* s4 = (bf16*)(ws + 4 * MB32);   // TV^T -> Kp[16][1024][1024]
  bf16* Wcat = (bf16*)(ws + 5 * MB32);
  bf16* Wb0 = Wcat;
  bf16* Wsb = Wcat + (1 << 20);
  bf16* Wpb = Wcat + 2 * (1 << 20);
  bf16* W1b = Wcat + 3 * (1 << 20);
  bf16* W2b = Wcat + 4 * (1 << 20);

  ew_convert<<<5120, 256, 0, stream>>>(Wmap, Wst, Wpr, Wp1, Wp2, Wcat);
  ew_h1<<<16384, 256, 0, stream>>>(x, a1, s0);

  {  // TV = H@Wsᵀ + noise -> s1
    GA g{};
    g.A = s0; g.lda = 1024; g.B = Wsb; g.ldb = 1024; g.K = 1024;
    g.noise = noise; g.Cb = s1; g.ldc = 1024;
    gemm_nt<M_TV><<<dim3(8, 128), 256, 0, stream>>>(g);
  }
  {  // P = H@Wpᵀ -> s2
    GA g{};
    g.A = s0; g.lda = 1024; g.B = Wpb; g.ldb = 1024; g.K = 1024;
    g.Cb = s2; g.ldc = 1024;
    gemm_nt<M_P><<<dim3(8, 128), 256, 0, stream>>>(g);
  }
  {  // E0 = TV@W0ᵀ - (TV - noise) -> s0 (H dead)
    GA g{};
    g.A = s1; g.lda = 1024; g.B = Wb0; g.ldb = 1024; g.K = 1024;
    g.noise = noise; g.TVb = s1; g.Cb = s0; g.ldc = 1024;
    gemm_nt<M_E0><<<dim3(8, 128), 256, 0, stream>>>(g);
  }
  tr_e0<<<dim3(16, 256), 256, 0, stream>>>(s0, s3);  // E0^T  (s0 free)
  tr_e0<<<dim3(16, 256), 256, 0, stream>>>(s1, s4);  // TV^T

  {  // C^T_j[r,c] = sum_n E0[n,r]*TV[n,c] -> s0[j]
    GA g{};
    g.A = s3; g.lda = 16384; g.B = s4; g.ldb = 16384; g.K = 1024;
    g.Cb = s0; g.ldc = 1024;
    gemm_nt<M_CT><<<dim3(8, 8, 16), 256, 0, stream>>>(g);
  }
  prefix_s<<<1024, 256, 0, stream>>>(s0, s0, Wb0);  // S' = W0 - lam*prefix

  {  // Kp_i = -lam * mask16 ∘ (P_i @ TV_iᵀ) -> s4 (TV^T dead)
    GA g{};
    g.A = s2; g.lda = 1024; g.B = s1; g.ldb = 1024; g.K = 1024;
    g.Cb = s4; g.ldc = 1024;
    gemm_nt<M_KP><<<dim3(8, 8, 16), 256, 0, stream>>>(g);
  }
  {  // x1_i = Kp_i@E0_i (tri-K) + P_i@S'_i + x -> d_out ; H2 -> s1
    GA g{};
    g.A = s4; g.lda = 1024;        // Kp chunk
    g.B = s3; g.ldb = 16384;       // E0^T (chunk col offset via z)
    g.A2 = s2; g.lda2 = 1024;      // P chunk
    g.B2 = s0; g.ldb2 = 1024;      // S' chunk
    g.xin = x; g.outf = out;
    g.alpha2 = a2; g.H2b = s1;     // fused tanh(alpha2*x1) (TV dead)
    gemm_nt<M_OUT><<<dim3(8, 8, 16), 256, 0, stream>>>(g);
  }

  {  // V = H2@Wp2ᵀ -> s0 (S' dead)
    GA g{};
    g.A = s1; g.lda = 1024; g.B = W2b; g.ldb = 1024; g.K = 1024;
    g.Cb = s0; g.ldc = 1024;
    gemm_nt<M_P><<<dim3(8, 128), 256, 0, stream>>>(g);
  }
  {  // out = gelu(H2@Wp1ᵀ)*V + x1
    GA g{};
    g.A = s1; g.lda = 1024; g.B = W1b; g.ldb = 1024; g.K = 1024;
    g.Vb = s0; g.outf = out;
    gemm_nt<M_U><<<dim3(8, 128), 256, 0, stream>>>(g);
  }
}

// Round 4
// 726.202 us; speedup vs baseline: 1.4043x; 1.1745x over previous
//
#include <hip/hip_runtime.h>
#include <math.h>

// ---------------------------------------------------------------------------
// TTT block, first-order expansion in lambda = LR*2/(B*D) = 1.2207e-6,
// chunked linear-attention form (chunk = 64 timesteps = 1024 rows):
//   H  = tanh(alpha1*x)                  rows r = t*16+b
//   TV = H@Wsᵀ + noise ; P = H@Wpᵀ ; E0 = TV@W0ᵀ - (TV - noise)
//   Cᵀ_j = E0ᵀ_j TV_j ; S'_i = W0 - lam * Σ_{j<i} Cᵀ_j  (excl prefix, fused W0)
//   x1_i = x + P_i@S'_iᵀ-form + Kp_i@E0_i,
//     Kp_i = -lam * mask16∘(P_i TV_iᵀ)  (triangular within chunk)
//   H2 = tanh(alpha2*x1) (fused into OUT epilogue)
//   out = gelu(H2@Wp1ᵀ)*(H2@Wp2ᵀ) + x1
//
// R4: geometry upgrade on the R3-verified skeleton. BM=BN=256, 8 waves
//     (512 threads), wave-tile 128x64 (2x4 wave grid, acc[8][4]).
//     Ring-4 LDS (4 slots x 32KB = 128KB), prefetch distance 2, fused
//     counted s_waitcnt+s_barrier (WAIT_BARRIER) — control flow, wait
//     constants (8/4/0: 4 gload_lds per wave per stage, unchanged), and
//     the T2 source-side swizzle family are IDENTICAL to R3 (which
//     measured 0 bank conflicts). Sync overhead per MFMA halves; LDS-read
//     bytes/MFMA 512->375; staged bytes per dispatch halve.
//     T5 setprio around MFMA cluster. T1 bijective XCD block swizzle
//     (all grids now 256 blocks, %8==0).
// ---------------------------------------------------------------------------

typedef __bf16 bf16;
typedef __attribute__((ext_vector_type(8))) __bf16 bf16x8;
typedef __attribute__((ext_vector_type(4))) __bf16 bf16x4;
typedef __attribute__((ext_vector_type(4))) float f32x4;

#define LAM 1.220703125e-6f  // LR * 2 / (B*D)

enum { M_TV = 0, M_P = 1, M_E0 = 2, M_CT = 3, M_KP = 4, M_OUT = 5, M_U = 6 };

struct GA {
  const bf16* A;  int lda;   // phase-1 operands
  const bf16* B;  int ldb;
  const bf16* A2; int lda2;  // phase-2 A (M_OUT: P)
  const bf16* B2; int ldb2;  // phase-2 B (M_OUT: S')
  int K;
  const float* noise;
  const float* xin;
  const float* alpha2;
  const bf16* TVb;
  const bf16* Vb;
  bf16* H2b;
  float* outf;
  bf16* Cb; int ldc;
};

// async 16B global->LDS (lds dest = wave-uniform base + lane*16)
#define GLOAD_LDS16(gp, lp)                                                   \
  __builtin_amdgcn_global_load_lds(                                           \
      (const __attribute__((address_space(1))) unsigned int*)(gp),            \
      (__attribute__((address_space(3))) unsigned int*)(lp), 16, 0, 0)

// Fused counted-wait + workgroup barrier. Single asm block so NOTHING can be
// scheduled between the waitcnt and the s_barrier, and the "memory" clobber
// keeps every LDS/global access on its own side. sched_barrier(0) pins the
// machine scheduler too (rule #18).
#define WAIT_BARRIER(N)                                                       \
  do {                                                                        \
    asm volatile("s_waitcnt vmcnt(" #N ")\n\ts_barrier" ::: "memory");        \
    __builtin_amdgcn_sched_barrier(0);                                        \
  } while (0)

// Stage one 256x32 A-tile + B-tile into LDS ring slot (async, 4 vmem/thread).
// LDS layout stays linear (chunk c -> row=c>>2, slot=c&3); the SOURCE
// k-block is swizzled: slot s of row r holds k-block s ^ ((r>>1)&3).
// 512 threads x 2 chunks x 16B = 16KB per matrix.
__device__ __forceinline__ void stage_tiles(const bf16* __restrict__ Ap, int lda,
                                            const bf16* __restrict__ Bp, int ldb,
                                            int k0, bf16* As, bf16* Bs, int tid) {
#pragma unroll
  for (int rr = 0; rr < 2; ++rr) {
    int c = tid + (rr << 9);                    // chunk 0..1023 (16B each)
    int row = c >> 2;
    int kb = (c & 3) ^ ((c >> 3) & 3);          // (c>>3)&3 == (row>>1)&3
    int lbase = ((tid & 448) + (rr << 9)) << 3; // wave-uniform LDS elem base
    GLOAD_LDS16(Ap + (size_t)row * lda + k0 + (kb << 3), As + lbase);
    GLOAD_LDS16(Bp + (size_t)row * ldb + k0 + (kb << 3), Bs + lbase);
  }
}

// 32 MFMAs on one staged 256x32 tile pair; wave-tile 128x64.
// gsw = ko ^ ((m>>1)&3) (swizzled read slot; row-dependence reduces to m).
__device__ __forceinline__ void compute_step(const bf16* As, const bf16* Bs,
                                             int wr, int wc, int m, int gsw,
                                             f32x4 acc[8][4]) {
  bf16x8 af[8], bfr[4];
#pragma unroll
  for (int i = 0; i < 8; ++i)
    af[i] = *(const bf16x8*)(As + (wr + i * 16 + m) * 32 + (gsw << 3));
#pragma unroll
  for (int j = 0; j < 4; ++j)
    bfr[j] = *(const bf16x8*)(Bs + (wc + j * 16 + m) * 32 + (gsw << 3));
  __builtin_amdgcn_s_setprio(1);
#pragma unroll
  for (int i = 0; i < 8; ++i) {
#pragma unroll
    for (int j = 0; j < 4; ++j)
      acc[i][j] =
          __builtin_amdgcn_mfma_f32_16x16x32_bf16(af[i], bfr[j], acc[i][j], 0, 0, 0);
  }
  __builtin_amdgcn_s_setprio(0);
}

// Map pipeline step index -> segment (phase-1 or, for M_OUT, phase-2) and stage.
template <int MODE>
__device__ __forceinline__ void stage_sel(const GA& g, int s, int steps1,
                                          const bf16* A1, const bf16* B1,
                                          const bf16* A2, const bf16* B2,
                                          bf16* Asb, bf16* Bsb, int tid) {
  if constexpr (MODE == M_OUT) {
    if (s >= steps1) {
      stage_tiles(A2, g.lda2, B2, g.ldb2, (s - steps1) << 5, Asb, Bsb, tid);
      return;
    }
  }
  stage_tiles(A1, g.lda, B1, g.ldb, s << 5, Asb, Bsb, tid);
}

// NT GEMM: C[r,c] = sum_k A[r,k]*B[c,k]; 256x256 tile, 512 threads (8 waves,
// 2x4 grid of 128x64 wave-tiles). blockIdx.z batches chunks (CT/KP/OUT).
template <int MODE>
__global__ __launch_bounds__(512, 2) void gemm_nt(GA g) {
  __shared__ __attribute__((aligned(16))) bf16 As[4][256 * 32];
  __shared__ __attribute__((aligned(16))) bf16 Bs[4][256 * 32];

  // T1: bijective XCD-chunk swizzle of the flat block id (all grids %8 == 0).
  const int gx = gridDim.x, gy = gridDim.y;
  const int nwg = gx * gy * (int)gridDim.z;
  int flat = blockIdx.x + gx * (blockIdx.y + gy * blockIdx.z);
  int swz = (flat & 7) * (nwg >> 3) + (flat >> 3);
  const int bx = swz % gx;
  int t1v = swz / gx;
  const int by = t1v % gy;
  const int bz = t1v / gy;

  const int c0 = bx << 8;
  const int r0 = by << 8;  // row-tile within chunk (or global when z==1)
  if constexpr (MODE == M_KP) {
    if (c0 > r0) return;  // strictly-above-diagonal tiles never read
  }

  size_t zA = 0, zB = 0, zC = 0;
  if constexpr (MODE == M_CT) { zA = (size_t)bz << 10; zB = zA; zC = (size_t)bz << 20; }
  if constexpr (MODE == M_KP) { zA = (size_t)bz << 20; zB = zA; zC = zA; }
  if constexpr (MODE == M_OUT) { zA = (size_t)bz << 20; zB = (size_t)bz << 10; }

  const int tid = threadIdx.x;
  const int lane = tid & 63, wv = tid >> 6;
  const int wr = (wv >> 2) << 7;   // 0 or 128
  const int wc = (wv & 3) << 6;    // 0,64,128,192
  const int m = lane & 15, ko = lane >> 4;
  const int gsw = ko ^ ((m >> 1) & 3);  // swizzled read slot

  f32x4 acc[8][4];
#pragma unroll
  for (int i = 0; i < 8; ++i) {
#pragma unroll
    for (int j = 0; j < 4; ++j) acc[i][j] = (f32x4){0.f, 0.f, 0.f, 0.f};
  }

  int K1 = g.K;
  if constexpr (MODE == M_OUT) K1 = r0 + 256;  // triangular (Kp cols > r0+255 are 0)
  const int steps1 = K1 >> 5;

  const bf16* A1 = g.A + zA + (size_t)r0 * g.lda;
  const bf16* B1 = g.B + zB + (size_t)c0 * g.ldb;
  const bf16* A2 = nullptr;
  const bf16* B2 = nullptr;
  int total = steps1;
  if constexpr (MODE == M_OUT) {
    A2 = g.A2 + zA + (size_t)r0 * g.lda2;
    B2 = g.B2 + zA + (size_t)c0 * g.ldb2;  // S' chunk bz
    total += 32;                            // phase-2: K=1024, BK=32
  }
  // total >= 32 for every launch config; always even.

  // -------- ring-4 pipeline, prefetch distance 2, counted vmcnt --------
  // Race proof: stage(s+2) overwrites slot[(s-2)&3], last read by
  // compute(s-2); every wave passed barrier(s-1) only after compute(s-2)'s
  // ds_reads completed everywhere, and stage(s+2) issues after barrier(s-1).
  stage_sel<MODE>(g, 0, steps1, A1, B1, A2, B2, As[0], Bs[0], tid);
  stage_sel<MODE>(g, 1, steps1, A1, B1, A2, B2, As[1], Bs[1], tid);

  int s = 0;
  for (; s < total - 2; ++s) {
    const int rn = (s + 2) & 3;
    stage_sel<MODE>(g, s + 2, steps1, A1, B1, A2, B2, As[rn], Bs[rn], tid);
    // wait: stage(s) landed (stages s+1,s+2 = 8 vmem/thread may stay in flight)
    WAIT_BARRIER(8);
    compute_step(As[s & 3], Bs[s & 3], wr, wc, m, gsw, acc);
  }
  // s == total-2: only stage(total-1) still in flight after this wait
  WAIT_BARRIER(4);
  compute_step(As[s & 3], Bs[s & 3], wr, wc, m, gsw, acc);
  ++s;
  WAIT_BARRIER(0);
  compute_step(As[s & 3], Bs[s & 3], wr, wc, m, gsw, acc);

  // C/D layout (m89/m91-verified): col = lane&15, row = (lane>>4)*4 + reg
#pragma unroll
  for (int i = 0; i < 8; ++i) {
#pragma unroll
    for (int j = 0; j < 4; ++j) {
      const int gc = c0 + wc + j * 16 + m;
#pragma unroll
      for (int rg = 0; rg < 4; ++rg) {
        const int grl = r0 + wr + i * 16 + ko * 4 + rg;
        float v = acc[i][j][rg];
        if constexpr (MODE == M_TV) {
          int t = grl >> 4, b = grl & 15;
          float tv = v + g.noise[((size_t)b << 20) + ((size_t)t << 10) + gc];
          g.Cb[(size_t)grl * g.ldc + gc] = (bf16)tv;
        } else if constexpr (MODE == M_P) {
          g.Cb[(size_t)grl * g.ldc + gc] = (bf16)v;
        } else if constexpr (MODE == M_CT) {
          g.Cb[zC + (size_t)grl * g.ldc + gc] = (bf16)v;
        } else if constexpr (MODE == M_E0) {
          int t = grl >> 4, b = grl & 15;
          size_t ni = ((size_t)b << 20) + ((size_t)t << 10) + gc;
          float tvv = (float)g.TVb[(size_t)grl * 1024 + gc];
          float e0 = v - (tvv - g.noise[ni]);  // state = tv - noise
          g.Cb[(size_t)grl * g.ldc + gc] = (bf16)e0;
        } else if constexpr (MODE == M_KP) {
          float sv = ((gc >> 4) <= (grl >> 4)) ? (-LAM * v) : 0.0f;
          g.Cb[zC + (size_t)grl * g.ldc + gc] = (bf16)sv;
        } else if constexpr (MODE == M_OUT) {
          int rgl = (bz << 10) + grl;
          int t = rgl >> 4, b = rgl & 15;
          size_t oi = ((size_t)b << 20) + ((size_t)t << 10) + gc;
          float x1 = v + g.xin[oi];
          g.outf[oi] = x1;
          g.H2b[oi] = (bf16)tanhf(g.alpha2[gc] * x1);  // fused norm_2
        } else if constexpr (MODE == M_U) {
          size_t oi = (size_t)grl * 1024 + gc;
          float u = v;
          float gl = 0.5f * u * (1.0f + erff(u * 0.70710678118654752f));
          g.outf[oi] = gl * (float)g.Vb[oi] + g.outf[oi];
        }
      }
    }
  }
}

// fp32 -> bf16 of the 5 weight matrices (concatenated dst)
__global__ void ew_convert(const float* w0, const float* w1, const float* w2,
                           const float* w3, const float* w4, bf16* dst) {
  int gid = blockIdx.x * 256 + threadIdx.x;
  int i4 = gid << 2;
  int mm = i4 >> 20;
  const float* src = (mm == 0) ? w0 : (mm == 1) ? w1 : (mm == 2) ? w2
                     : (mm == 3) ? w3 : w4;
  int off = i4 & 1048575;
  float4 v = *(const float4*)(src + off);
  bf16x4 o;
  o[0] = (bf16)v.x; o[1] = (bf16)v.y; o[2] = (bf16)v.z; o[3] = (bf16)v.w;
  *(bf16x4*)(dst + i4) = o;
}

// H[(t*16+b), d] = bf16(tanh(alpha1[d] * x[b,t,d]))
__global__ void ew_h1(const float* __restrict__ x, const float* __restrict__ a1,
                      bf16* __restrict__ H) {
  int gid = blockIdx.x * 256 + threadIdx.x;
  int i4 = gid << 2;
  int d = i4 & 1023;
  int t = (i4 >> 10) & 1023;
  int b = i4 >> 20;
  float4 xv = *(const float4*)(x + i4);
  float4 av = *(const float4*)(a1 + d);
  bf16x4 o;
  o[0] = (bf16)tanhf(av.x * xv.x);
  o[1] = (bf16)tanhf(av.y * xv.y);
  o[2] = (bf16)tanhf(av.z * xv.z);
  o[3] = (bf16)tanhf(av.w * xv.w);
  *(bf16x4*)(H + (((size_t)((t << 4) + b)) << 10) + d) = o;
}

// S'[j] = W0 - lam * (exclusive prefix of C over chunks); in-place safe
__global__ void prefix_s(const bf16* __restrict__ C, bf16* __restrict__ S,
                         const bf16* __restrict__ W0) {
  int gid = blockIdx.x * 256 + threadIdx.x;  // 262144 threads
  size_t base = (size_t)gid << 2;
  bf16x4 wv = *(const bf16x4*)(W0 + base);
  float w0 = (float)wv[0], w1 = (float)wv[1], w2 = (float)wv[2],
        w3 = (float)wv[3];
  float ac0 = 0.f, ac1 = 0.f, ac2 = 0.f, ac3 = 0.f;
#pragma unroll
  for (int j = 0; j < 16; ++j) {
    size_t off = ((size_t)j << 20) + base;
    bf16x4 c = *(const bf16x4*)(C + off);
    bf16x4 o;
    o[0] = (bf16)(w0 - LAM * ac0);
    o[1] = (bf16)(w1 - LAM * ac1);
    o[2] = (bf16)(w2 - LAM * ac2);
    o[3] = (bf16)(w3 - LAM * ac3);
    *(bf16x4*)(S + off) = o;
    ac0 += (float)c[0]; ac1 += (float)c[1];
    ac2 += (float)c[2]; ac3 += (float)c[3];
  }
}

// [16384 x 1024] -> [1024 x 16384] bf16 transpose, 64x64 LDS tiles
__global__ __launch_bounds__(256) void tr_e0(const bf16* __restrict__ in,
                                             bf16* __restrict__ out) {
  __shared__ bf16 tile[64][72];
  int c0 = blockIdx.x << 6;
  int r0 = blockIdx.y << 6;
  int tid = threadIdx.x;
  int lr = tid >> 4;
  int lc = (tid & 15) << 2;
#pragma unroll
  for (int ph = 0; ph < 4; ++ph) {
    int row = lr + (ph << 4);
    bf16x4 v = *(const bf16x4*)(in + (size_t)(r0 + row) * 1024 + c0 + lc);
    *(bf16x4*)(&tile[row][lc]) = v;
  }
  __syncthreads();
#pragma unroll
  for (int ph = 0; ph < 4; ++ph) {
    int oc = lr + (ph << 4);
    bf16x4 v;
    v[0] = tile[lc + 0][oc];
    v[1] = tile[lc + 1][oc];
    v[2] = tile[lc + 2][oc];
    v[3] = tile[lc + 3][oc];
    *(bf16x4*)(out + (size_t)(c0 + oc) * 16384 + r0 + lc) = v;
  }
}

extern "C" void kernel_launch(void* const* d_in, const int* in_sizes, int n_in,
                              void* d_out, int out_size, void* d_ws,
                              size_t ws_size, hipStream_t stream) {
  (void)in_sizes; (void)n_in; (void)out_size;
  const float* x = (const float*)d_in[0];
  const float* noise = (const float*)d_in[1];
  const float* a1 = (const float*)d_in[2];
  const float* a2 = (const float*)d_in[3];
  const float* Wmap = (const float*)d_in[4];
  const float* Wst = (const float*)d_in[5];
  const float* Wpr = (const float*)d_in[6];
  const float* Wp1 = (const float*)d_in[7];
  const float* Wp2 = (const float*)d_in[8];
  float* out = (float*)d_out;

  const size_t MB32 = (size_t)16384 * 1024 * 2;  // 32 MiB
  const size_t NEED = 5 * MB32 + 5 * (size_t)1048576 * 2;  // 170 MiB
  if (ws_size < NEED) return;  // insufficient scratch; fail loudly

  char* ws = (char*)d_ws;
  bf16* s0 = (bf16*)(ws);              // H -> E0 -> C^T -> S' -> V
  bf16* s1 = (bf16*)(ws + MB32);       // TV -> H2
  bf16* s2 = (bf16*)(ws + 2 * MB32);   // P
  bf16* s3 = (bf16*)(ws + 3 * MB32);   // E0^T [1024 x 16384]
  bf16* s4 = (bf16*)(ws + 4 * MB32);   // TV^T -> Kp[16][1024][1024]
  bf16* Wcat = (bf16*)(ws + 5 * MB32);
  bf16* Wb0 = Wcat;
  bf16* Wsb = Wcat + (1 << 20);
  bf16* Wpb = Wcat + 2 * (1 << 20);
  bf16* W1b = Wcat + 3 * (1 << 20);
  bf16* W2b = Wcat + 4 * (1 << 20);

  ew_convert<<<5120, 256, 0, stream>>>(Wmap, Wst, Wpr, Wp1, Wp2, Wcat);
  ew_h1<<<16384, 256, 0, stream>>>(x, a1, s0);

  {  // TV = H@Wsᵀ + noise -> s1
    GA g{};
    g.A = s0; g.lda = 1024; g.B = Wsb; g.ldb = 1024; g.K = 1024;
    g.noise = noise; g.Cb = s1; g.ldc = 1024;
    gemm_nt<M_TV><<<dim3(4, 64), 512, 0, stream>>>(g);
  }
  {  // P = H@Wpᵀ -> s2
    GA g{};
    g.A = s0; g.lda = 1024; g.B = Wpb; g.ldb = 1024; g.K = 1024;
    g.Cb = s2; g.ldc = 1024;
    gemm_nt<M_P><<<dim3(4, 64), 512, 0, stream>>>(g);
  }
  {  // E0 = TV@W0ᵀ - (TV - noise) -> s0 (H dead)
    GA g{};
    g.A = s1; g.lda = 1024; g.B = Wb0; g.ldb = 1024; g.K = 1024;
    g.noise = noise; g.TVb = s1; g.Cb = s0; g.ldc = 1024;
    gemm_nt<M_E0><<<dim3(4, 64), 512, 0, stream>>>(g);
  }
  tr_e0<<<dim3(16, 256), 256, 0, stream>>>(s0, s3);  // E0^T  (s0 free)
  tr_e0<<<dim3(16, 256), 256, 0, stream>>>(s1, s4);  // TV^T

  {  // C^T_j[r,c] = sum_n E0[n,r]*TV[n,c] -> s0[j]
    GA g{};
    g.A = s3; g.lda = 16384; g.B = s4; g.ldb = 16384; g.K = 1024;
    g.Cb = s0; g.ldc = 1024;
    gemm_nt<M_CT><<<dim3(4, 4, 16), 512, 0, stream>>>(g);
  }
  prefix_s<<<1024, 256, 0, stream>>>(s0, s0, Wb0);  // S' = W0 - lam*prefix

  {  // Kp_i = -lam * mask16 ∘ (P_i @ TV_iᵀ) -> s4 (TV^T dead)
    GA g{};
    g.A = s2; g.lda = 1024; g.B = s1; g.ldb = 1024; g.K = 1024;
    g.Cb = s4; g.ldc = 1024;
    gemm_nt<M_KP><<<dim3(4, 4, 16), 512, 0, stream>>>(g);
  }
  {  // x1_i = Kp_i@E0_i (tri-K) + P_i@S'_i + x -> d_out ; H2 -> s1
    GA g{};
    g.A = s4; g.lda = 1024;        // Kp chunk
    g.B = s3; g.ldb = 16384;       // E0^T (chunk col offset via z)
    g.A2 = s2; g.lda2 = 1024;      // P chunk
    g.B2 = s0; g.ldb2 = 1024;      // S' chunk
    g.xin = x; g.outf = out;
    g.alpha2 = a2; g.H2b = s1;     // fused tanh(alpha2*x1) (TV dead)
    gemm_nt<M_OUT><<<dim3(4, 4, 16), 512, 0, stream>>>(g);
  }

  {  // V = H2@Wp2ᵀ -> s0 (S' dead)
    GA g{};
    g.A = s1; g.lda = 1024; g.B = W2b; g.ldb = 1024; g.K = 1024;
    g.Cb = s0; g.ldc = 1024;
    gemm_nt<M_P><<<dim3(4, 64), 512, 0, stream>>>(g);
  }
  {  // out = gelu(H2@Wp1ᵀ)*V + x1
    GA g{};
    g.A = s1; g.lda = 1024; g.B = W1b; g.ldb = 1024; g.K = 1024;
    g.Vb = s0; g.outf = out;
    gemm_nt<M_U><<<dim3(4, 64), 512, 0, stream>>>(g);
  }
}